// Round 1
// baseline (100.011 us; speedup 1.0000x reference)
//
#include <hip/hip_runtime.h>

// Problem constants
#define B_ 4
#define E_ 1024
#define S_ 2048
#define H_ 16
#define K_ 1024

#define NCH 32          // scan chunks along S
#define CS  (S_/NCH)    // 64

typedef __bf16 bf16x8 __attribute__((ext_vector_type(8)));
typedef float  f32x4  __attribute__((ext_vector_type(4)));

__device__ __forceinline__ unsigned short f2bf(float f) {
  unsigned u = __float_as_uint(f);
  u += 0x7fffu + ((u >> 16) & 1u);   // round-to-nearest-even
  return (unsigned short)(u >> 16);
}
__device__ __forceinline__ float bf2f(unsigned short h) {
  return __uint_as_float(((unsigned)h) << 16);
}

// ---------------------------------------------------------------------------
// fp32 -> bf16 weight conversion (in_w -> W1b, out_w -> W2b), no transpose.
// ---------------------------------------------------------------------------
__global__ __launch_bounds__(256)
void convert_weights(const float* __restrict__ a, const float* __restrict__ c,
                     unsigned short* __restrict__ wa, unsigned short* __restrict__ wb)
{
  const int per = (E_ * E_) / 4;                 // float4s per matrix
  int i = blockIdx.x * 256 + threadIdx.x;        // 0 .. 2*per-1
  const float4* src = (i < per) ? (const float4*)a : (const float4*)c;
  unsigned short* dst = (i < per) ? wa : wb;
  int j = (i < per) ? i : i - per;
  float4 v = src[j];
  ushort4 o;
  o.x = f2bf(v.x); o.y = f2bf(v.y); o.z = f2bf(v.z); o.w = f2bf(v.w);
  *(ushort4*)(dst + (long)j * 4) = o;
}

// ---------------------------------------------------------------------------
// x (B,E,S) fp32 -> Xt (B,S,E) bf16 : LDS-tiled transpose + convert
// ---------------------------------------------------------------------------
__global__ __launch_bounds__(256)
void transpose_convert(const float* __restrict__ x, unsigned short* __restrict__ xt)
{
  __shared__ float t[64][65];
  const int b  = blockIdx.z;
  const int e0 = blockIdx.y * 64;
  const int s0 = blockIdx.x * 64;
  const int tx = threadIdx.x & 63, ty = threadIdx.x >> 6;  // ty in 0..3

  const float* xp = x + ((long)b * E_ + e0) * S_ + s0;
#pragma unroll
  for (int r = 0; r < 16; ++r) {
    int row = r * 4 + ty;                          // e-offset within tile
    t[row][tx] = xp[(long)row * S_ + tx];
  }
  __syncthreads();
  unsigned short* xo = xt + ((long)b * S_ + s0) * E_ + e0;
#pragma unroll
  for (int r = 0; r < 16; ++r) {
    int srow = r * 4 + ty;                         // s-offset within tile
    xo[(long)srow * E_ + tx] = f2bf(t[tx][srow]);
  }
}

// ---------------------------------------------------------------------------
// GEMM  C[b] (M x N) = A[b] (M x K) * Bt[b] (N x K)^T  + bias
// bf16 inputs, fp32 accumulate; 128x128 tile, BK=64, 4 waves (2x2),
// mfma_f32_16x16x32_bf16, global_load_lds width-16 staging (m97 structure).
// ---------------------------------------------------------------------------
template<bool OUT_BF16, bool BIAS_ROW>
__global__ __launch_bounds__(256)
void gemm_abt(const unsigned short* __restrict__ A, long sA,
              const unsigned short* __restrict__ Bt, long sB,
              void* __restrict__ Cout, long sC,
              const float* __restrict__ bias,
              int K, int NT, int ldc)
{
  __shared__ unsigned short As[128 * 64];
  __shared__ unsigned short Bs[128 * 64];

  const int b  = blockIdx.y;
  const int tm = blockIdx.x / NT, tn = blockIdx.x % NT;
  const unsigned short* Ab = A  + (long)b * sA + (long)tm * 128 * K;
  const unsigned short* Bb = Bt + (long)b * sB + (long)tn * 128 * K;

  const int tid  = threadIdx.x;
  const int lane = tid & 63, wid = tid >> 6;
  const int wm = wid >> 1, wn = wid & 1;     // 2x2 waves, 64x64 each
  const int lr = lane & 15, lg = lane >> 4;

  f32x4 acc[4][4] = {};

  for (int kt = 0; kt < K; kt += 64) {
    // stage A,B tiles: 16KB each = 4 insts x 256 thr x 16B
#pragma unroll
    for (int i = 0; i < 4; ++i) {
      int chunk = i * 256 + tid;               // 16B chunk id; 8 chunks/row
      int row = chunk >> 3;
      int kc  = (chunk & 7) << 3;
      int wbase = (i * 256 + wid * 64) << 3;   // wave-uniform LDS element base
      __builtin_amdgcn_global_load_lds(
          (const __attribute__((address_space(1))) void*)(Ab + (long)row * K + kt + kc),
          (__attribute__((address_space(3))) void*)(As + wbase), 16, 0, 0);
      __builtin_amdgcn_global_load_lds(
          (const __attribute__((address_space(1))) void*)(Bb + (long)row * K + kt + kc),
          (__attribute__((address_space(3))) void*)(Bs + wbase), 16, 0, 0);
    }
    __syncthreads();

#pragma unroll
    for (int ks = 0; ks < 2; ++ks) {
      const int koff = ks * 32 + lg * 8;
      bf16x8 af[4], bfr[4];
#pragma unroll
      for (int mf = 0; mf < 4; ++mf)
        af[mf] = *(const bf16x8*)(As + (wm * 64 + mf * 16 + lr) * 64 + koff);
#pragma unroll
      for (int nf = 0; nf < 4; ++nf)
        bfr[nf] = *(const bf16x8*)(Bs + (wn * 64 + nf * 16 + lr) * 64 + koff);
#pragma unroll
      for (int mf = 0; mf < 4; ++mf)
#pragma unroll
        for (int nf = 0; nf < 4; ++nf)
          acc[mf][nf] = __builtin_amdgcn_mfma_f32_16x16x32_bf16(
              af[mf], bfr[nf], acc[mf][nf], 0, 0, 0);
    }
    __syncthreads();
  }

  // epilogue: D layout col = lane&15, row = (lane>>4)*4 + j  [m89/m91-verified]
  const int m0 = tm * 128 + wm * 64, n0 = tn * 128 + wn * 64;
#pragma unroll
  for (int mf = 0; mf < 4; ++mf) {
#pragma unroll
    for (int nf = 0; nf < 4; ++nf) {
#pragma unroll
      for (int j = 0; j < 4; ++j) {
        int r = m0 + mf * 16 + lg * 4 + j;
        int c = n0 + nf * 16 + lr;
        float v = acc[mf][nf][j] + (BIAS_ROW ? bias[r] : bias[c]);
        if constexpr (OUT_BF16)
          ((unsigned short*)Cout)[(long)b * sC + (long)r * ldc + c] = f2bf(v);
        else
          ((float*)Cout)[(long)b * sC + (long)r * ldc + c] = v;
      }
    }
  }
}

// ---------------------------------------------------------------------------
// Mixing = causal prefix scan along S (two-pass, chunked).
//   h < 8 : z[s,c] = mix_w[h,s] * sum_{t<=s} y[t,c]            + mix_b[h,s]
//   h >= 8: z[s,c] = sum_{t<=s} mix_w[h,t] * y[t,c]            + mix_b[h,s]
// Yt/Zt layout (B,S,E) bf16; threads cover channels -> coalesced.
// ---------------------------------------------------------------------------
__global__ __launch_bounds__(256)
void scan_part(const unsigned short* __restrict__ yt, const float* __restrict__ mixw,
               float* __restrict__ part)
{
  const int b  = blockIdx.z;
  const int c  = blockIdx.y * 256 + threadIdx.x;
  const int ch = blockIdx.x;
  const int h  = c >> 6;                        // wave-uniform
  const unsigned short* yp = yt + ((long)b * S_ + ch * CS) * E_ + c;
  float sum = 0.f;
  if (h < 8) {
#pragma unroll 4
    for (int s = 0; s < CS; ++s) sum += bf2f(yp[(long)s * E_]);
  } else {
    const float* mw = mixw + (long)h * S_ + ch * CS;
#pragma unroll 4
    for (int s = 0; s < CS; ++s) sum += bf2f(yp[(long)s * E_]) * mw[s];
  }
  part[((long)b * NCH + ch) * E_ + c] = sum;
}

__global__ __launch_bounds__(256)
void scan_final(const unsigned short* __restrict__ yt, const float* __restrict__ mixw,
                const float* __restrict__ mixb, const float* __restrict__ part,
                unsigned short* __restrict__ zt)
{
  const int b  = blockIdx.z;
  const int c  = blockIdx.y * 256 + threadIdx.x;
  const int ch = blockIdx.x;
  const int h  = c >> 6;
  float acc = 0.f;
  for (int p = 0; p < ch; ++p) acc += part[((long)b * NCH + p) * E_ + c];
  const unsigned short* yp = yt + ((long)b * S_ + ch * CS) * E_ + c;
  unsigned short*       zp = zt + ((long)b * S_ + ch * CS) * E_ + c;
  const float* mw = mixw + (long)h * S_ + ch * CS;
  const float* mb = mixb + (long)h * S_ + ch * CS;
  if (h < 8) {
    for (int s = 0; s < CS; ++s) {
      acc += bf2f(yp[(long)s * E_]);
      zp[(long)s * E_] = f2bf(fmaf(acc, mw[s], mb[s]));
    }
  } else {
    for (int s = 0; s < CS; ++s) {
      acc += bf2f(yp[(long)s * E_]) * mw[s];
      zp[(long)s * E_] = f2bf(acc + mb[s]);
    }
  }
}

// ---------------------------------------------------------------------------
extern "C" void kernel_launch(void* const* d_in, const int* in_sizes, int n_in,
                              void* d_out, int out_size, void* d_ws, size_t ws_size,
                              hipStream_t stream)
{
  (void)in_sizes; (void)n_in; (void)out_size; (void)ws_size;
  const float* x     = (const float*)d_in[0];
  const float* in_w  = (const float*)d_in[1];
  const float* in_b  = (const float*)d_in[2];
  const float* out_w = (const float*)d_in[3];
  const float* out_b = (const float*)d_in[4];
  const float* mix_w = (const float*)d_in[5];
  const float* mix_b = (const float*)d_in[6];

  char* ws = (char*)d_ws;
  unsigned short* Xt  = (unsigned short*)(ws);                          // 16 MB (reused as Zt)
  unsigned short* Yt  = (unsigned short*)(ws + (size_t)16 * 1024 * 1024); // 16 MB
  unsigned short* W1b = (unsigned short*)(ws + (size_t)32 * 1024 * 1024); // 2 MB
  unsigned short* W2b = (unsigned short*)(ws + (size_t)34 * 1024 * 1024); // 2 MB
  float*          part = (float*)(ws + (size_t)36 * 1024 * 1024);         // 512 KB
  unsigned short* Zt  = Xt;   // Xt dead after GEMM1

  // 1) weights fp32 -> bf16
  convert_weights<<<dim3((2 * E_ * E_ / 4) / 256), 256, 0, stream>>>(in_w, out_w, W1b, W2b);

  // 2) x (B,E,S) -> Xt (B,S,E) bf16
  transpose_convert<<<dim3(S_ / 64, E_ / 64, B_), 256, 0, stream>>>(x, Xt);

  // 3) in_proj: Yt[b] (S x E) = Xt[b] (S x K) * W1b (E x K)^T + in_b[col]
  gemm_abt<true, false><<<dim3((S_ / 128) * (E_ / 128), B_), 256, 0, stream>>>(
      Xt, (long)S_ * K_, W1b, 0, Yt, (long)S_ * E_, in_b, K_, E_ / 128, E_);

  // 4) causal mixing via chunked prefix scan
  scan_part<<<dim3(NCH, E_ / 256, B_), 256, 0, stream>>>(Yt, mix_w, part);
  scan_final<<<dim3(NCH, E_ / 256, B_), 256, 0, stream>>>(Yt, mix_w, mix_b, part, Zt);

  // 5) out_proj: out[b] (E x S) = W2b (E x K) * Zt[b] (S x K)^T + out_b[row]
  gemm_abt<false, true><<<dim3((E_ / 128) * (S_ / 128), B_), 256, 0, stream>>>(
      W2b, 0, Zt, (long)S_ * K_, d_out, (long)E_ * S_, out_b, K_, S_ / 128, S_);
}

// Round 2
// 95.873 us; speedup vs baseline: 1.0432x; 1.0432x over previous
//
#include <hip/hip_runtime.h>

// Problem constants
#define B_ 4
#define E_ 1024
#define S_ 2048
#define H_ 16
#define K_ 1024

#define NCH 32          // scan chunks along S
#define CS  (S_/NCH)    // 64

typedef __bf16 bf16x8 __attribute__((ext_vector_type(8)));
typedef float  f32x4  __attribute__((ext_vector_type(4)));

__device__ __forceinline__ unsigned short f2bf(float f) {
  unsigned u = __float_as_uint(f);
  u += 0x7fffu + ((u >> 16) & 1u);   // round-to-nearest-even
  return (unsigned short)(u >> 16);
}
__device__ __forceinline__ float bf2f(unsigned short h) {
  return __uint_as_float(((unsigned)h) << 16);
}

// ---------------------------------------------------------------------------
// fp32 -> bf16 weight conversion (in_w -> W1b, out_w -> W2b), no transpose.
// ---------------------------------------------------------------------------
__global__ __launch_bounds__(256)
void convert_weights(const float* __restrict__ a, const float* __restrict__ c,
                     unsigned short* __restrict__ wa, unsigned short* __restrict__ wb)
{
  const int per = (E_ * E_) / 4;
  int i = blockIdx.x * 256 + threadIdx.x;
  const float4* src = (i < per) ? (const float4*)a : (const float4*)c;
  unsigned short* dst = (i < per) ? wa : wb;
  int j = (i < per) ? i : i - per;
  float4 v = src[j];
  ushort4 o;
  o.x = f2bf(v.x); o.y = f2bf(v.y); o.z = f2bf(v.z); o.w = f2bf(v.w);
  *(ushort4*)(dst + (long)j * 4) = o;
}

// ---------------------------------------------------------------------------
// x (B,E,S) fp32 -> Xt (B,S,E) bf16 : LDS-tiled transpose + convert
// ---------------------------------------------------------------------------
__global__ __launch_bounds__(256)
void transpose_convert(const float* __restrict__ x, unsigned short* __restrict__ xt)
{
  __shared__ float t[64][65];
  const int b  = blockIdx.z;
  const int e0 = blockIdx.y * 64;
  const int s0 = blockIdx.x * 64;
  const int tx = threadIdx.x & 63, ty = threadIdx.x >> 6;

  const float* xp = x + ((long)b * E_ + e0) * S_ + s0;
#pragma unroll
  for (int r = 0; r < 16; ++r) {
    int row = r * 4 + ty;                          // e-offset within tile
    t[row][tx] = xp[(long)row * S_ + tx];
  }
  __syncthreads();
  unsigned short* xo = xt + ((long)b * S_ + s0) * E_ + e0;
#pragma unroll
  for (int p = 0; p < 2; ++p) {
    int s = p * 32 + (threadIdx.x >> 3);           // s-offset in tile
    int e = (threadIdx.x & 7) * 8;                 // e-offset in tile
    unsigned short v[8];
#pragma unroll
    for (int j = 0; j < 8; ++j) v[j] = f2bf(t[e + j][s]);
    *(ushort4*)(xo + (long)s * E_ + e)     = make_ushort4(v[0], v[1], v[2], v[3]);
    *(ushort4*)(xo + (long)s * E_ + e + 4) = make_ushort4(v[4], v[5], v[6], v[7]);
  }
}

// ---------------------------------------------------------------------------
// 8-phase GEMM: C (8192 x 1024) = A (8192 x 1024) * Bw (1024 x 1024)^T + bias
// BM=256, BN=128, BK=64; 512 thr (8 waves = 2M x 4N); double-buffered LDS
// 2 x (A[2][256][32] + B[2][128][32]) bf16 = 96 KiB, XOR-swizzled.
// Counted vmcnt(6) at even phases (T4); setprio around MFMA (T5).
// VARIANT 0: C = Yt bf16 row-major ld=1024, bias by col.
// VARIANT 1: C = out fp32 written transposed into (B_,E_,S_), bias by col.
// ---------------------------------------------------------------------------
#define BB1 49152      // buffer 1 byte offset (48 KiB per buffer)

__device__ __forceinline__ void stage_a(char* smem, const unsigned short* __restrict__ Ab,
                                        int bb, int t, int ks, int tid, int wid) {
#pragma unroll
  for (int j = 0; j < 2; ++j) {
    int chunk = j * 512 + tid;
    int row = chunk >> 2;
    int cb  = (chunk & 3) << 4;
    int cbs = cb ^ (((row >> 1) & 3) << 4);        // inverse(=same) swizzle on source
    const unsigned short* src = Ab + (long)row * K_ + t * 64 + ks * 32 + (cbs >> 1);
    __builtin_amdgcn_global_load_lds(
        (const __attribute__((address_space(1))) void*)src,
        (__attribute__((address_space(3))) void*)(smem + bb + ks * 16384 + j * 8192 + wid * 1024),
        16, 0, 0);
  }
}

__device__ __forceinline__ void stage_b(char* smem, const unsigned short* __restrict__ Bb,
                                        int bb, int t, int ks, int tid, int wid) {
  int row = tid >> 2;                              // 0..127
  int cb  = (tid & 3) << 4;
  int cbs = cb ^ (((row >> 1) & 3) << 4);
  const unsigned short* src = Bb + (long)row * K_ + t * 64 + ks * 32 + (cbs >> 1);
  __builtin_amdgcn_global_load_lds(
      (const __attribute__((address_space(1))) void*)src,
      (__attribute__((address_space(3))) void*)(smem + bb + 32768 + ks * 8192 + wid * 1024),
      16, 0, 0);
}

template<int MH>
__device__ __forceinline__ void phase_reads(const char* smem, int bb, int ks,
    int wm, int wn, int lr, int lg, bf16x8 af[4], bf16x8 bfr[2]) {
#pragma unroll
  for (int q = 0; q < 4; ++q) {
    int row = wm * 128 + (MH * 4 + q) * 16 + lr;
    int cb  = (lg * 16) ^ (((row >> 1) & 3) << 4);
    af[q] = *(const bf16x8*)(smem + bb + ks * 16384 + row * 64 + cb);
  }
  if (MH == 0) {
#pragma unroll
    for (int q = 0; q < 2; ++q) {
      int row = wn * 32 + q * 16 + lr;
      int cb  = (lg * 16) ^ (((row >> 1) & 3) << 4);
      bfr[q] = *(const bf16x8*)(smem + bb + 32768 + ks * 8192 + row * 64 + cb);
    }
  }
}

template<int MH>
__device__ __forceinline__ void phase_mfma(const bf16x8 af[4], const bf16x8 bfr[2],
                                           f32x4 acc[8][2]) {
  __builtin_amdgcn_s_setprio(1);
#pragma unroll
  for (int q = 0; q < 4; ++q)
#pragma unroll
    for (int nf = 0; nf < 2; ++nf)
      acc[MH * 4 + q][nf] = __builtin_amdgcn_mfma_f32_16x16x32_bf16(
          af[q], bfr[nf], acc[MH * 4 + q][nf], 0, 0, 0);
  __builtin_amdgcn_s_setprio(0);
}

#define FENCE asm volatile("" ::: "memory")
#define BAR do { FENCE; __builtin_amdgcn_s_barrier(); FENCE; } while (0)
#define VM(n) asm volatile("s_waitcnt vmcnt(" #n ")" ::: "memory")
#define NOWAIT (void)0

#define PH(bb, ks, mh, STAGE, WAIT) do {                        \
    bf16x8 af[4];                                               \
    phase_reads<mh>(smem, bb, ks, wm, wn, lr, lg, af, bfr);     \
    STAGE;                                                      \
    WAIT;                                                       \
    BAR;                                                        \
    asm volatile("s_waitcnt lgkmcnt(0)" ::: "memory");          \
    phase_mfma<mh>(af, bfr, acc);                               \
    BAR;                                                        \
  } while (0)

template<int VARIANT>
__global__ __launch_bounds__(512, 2)
void gemm8p(const unsigned short* __restrict__ A, const unsigned short* __restrict__ Bw,
            void* __restrict__ Cout, const float* __restrict__ bias)
{
  extern __shared__ char smem[];
  const int tid  = threadIdx.x;
  const int lane = tid & 63, wid = tid >> 6;
  const int wm = wid >> 2, wn = wid & 3;           // 2M x 4N waves
  const int lr = lane & 15, lg = lane >> 4;
  const int tn = blockIdx.x & 7;                   // 8 n-tiles; tn==XCD id (L2 share)
  const int tm = blockIdx.x >> 3;                  // 32 m-tiles

  const unsigned short* Ab = A  + (long)tm * 256 * K_;
  const unsigned short* Bb = Bw + (long)tn * 128 * K_;

  f32x4 acc[8][2] = {};
  bf16x8 bfr[2];

  // Prologue: t0.Ak0 t0.Bk0 t0.Ak1 t0.Bk1 t1.Ak0 t1.Bk0 (9 loads), vmcnt(6)
  stage_a(smem, Ab, 0, 0, 0, tid, wid);
  stage_b(smem, Bb, 0, 0, 0, tid, wid);
  stage_a(smem, Ab, 0, 0, 1, tid, wid);
  stage_b(smem, Bb, 0, 0, 1, tid, wid);
  stage_a(smem, Ab, BB1, 1, 0, tid, wid);
  stage_b(smem, Bb, BB1, 1, 0, tid, wid);
  VM(6);
  BAR;

  for (int i = 0; i < 7; ++i) {                    // NI-1 full iterations
    const int t1 = 2 * i + 1, t2 = 2 * i + 2, t3 = 2 * i + 3;
    PH(0,   0, 0, stage_a(smem, Ab, BB1, t1, 1, tid, wid), NOWAIT);
    PH(0,   0, 1, stage_b(smem, Bb, BB1, t1, 1, tid, wid), VM(6));
    PH(0,   1, 0, stage_a(smem, Ab, 0,   t2, 0, tid, wid), NOWAIT);
    PH(0,   1, 1, stage_b(smem, Bb, 0,   t2, 0, tid, wid), VM(6));
    PH(BB1, 0, 0, stage_a(smem, Ab, 0,   t2, 1, tid, wid), NOWAIT);
    PH(BB1, 0, 1, stage_b(smem, Bb, 0,   t2, 1, tid, wid), VM(6));
    PH(BB1, 1, 0, stage_a(smem, Ab, BB1, t3, 0, tid, wid), NOWAIT);
    PH(BB1, 1, 1, stage_b(smem, Bb, BB1, t3, 0, tid, wid), VM(6));
  }
  // Final iteration (tiles 14,15): stage only t15.k1; drain 6 -> 3 -> 0.
  PH(0,   0, 0, stage_a(smem, Ab, BB1, 15, 1, tid, wid), NOWAIT);
  PH(0,   0, 1, stage_b(smem, Bb, BB1, 15, 1, tid, wid), VM(6));
  PH(0,   1, 0, NOWAIT, NOWAIT);
  PH(0,   1, 1, NOWAIT, VM(3));
  PH(BB1, 0, 0, NOWAIT, NOWAIT);
  PH(BB1, 0, 1, NOWAIT, VM(0));
  PH(BB1, 1, 0, NOWAIT, NOWAIT);
  PH(BB1, 1, 1, NOWAIT, NOWAIT);

  // Epilogue. C/D frag: col = lane&15, row = (lane>>4)*4 + j  [m89/m91]
#pragma unroll
  for (int nf = 0; nf < 2; ++nf) {
    const int c = tn * 128 + wn * 32 + nf * 16 + lr;
    const float bv = bias[c];
#pragma unroll
    for (int mf = 0; mf < 8; ++mf) {
      const int r0 = tm * 256 + wm * 128 + mf * 16 + lg * 4;
      if constexpr (VARIANT == 0) {
#pragma unroll
        for (int j = 0; j < 4; ++j)
          ((unsigned short*)Cout)[(long)(r0 + j) * E_ + c] = f2bf(acc[mf][nf][j] + bv);
      } else {
        const int s = r0 & (S_ - 1);
        const int b = r0 >> 11;                    // 256-row tile never crosses batch
        float4 v;
        v.x = acc[mf][nf][0] + bv; v.y = acc[mf][nf][1] + bv;
        v.z = acc[mf][nf][2] + bv; v.w = acc[mf][nf][3] + bv;
        *(float4*)((float*)Cout + ((long)b * E_ + c) * S_ + s) = v;
      }
    }
  }
}

// ---------------------------------------------------------------------------
// Mixing = causal prefix scan along S (two-pass, chunked).
// ---------------------------------------------------------------------------
__global__ __launch_bounds__(256)
void scan_part(const unsigned short* __restrict__ yt, const float* __restrict__ mixw,
               float* __restrict__ part)
{
  const int b  = blockIdx.z;
  const int c  = blockIdx.y * 256 + threadIdx.x;
  const int ch = blockIdx.x;
  const int h  = c >> 6;
  const unsigned short* yp = yt + ((long)b * S_ + ch * CS) * E_ + c;
  float sum = 0.f;
  if (h < 8) {
#pragma unroll 4
    for (int s = 0; s < CS; ++s) sum += bf2f(yp[(long)s * E_]);
  } else {
    const float* mw = mixw + (long)h * S_ + ch * CS;
#pragma unroll 4
    for (int s = 0; s < CS; ++s) sum += bf2f(yp[(long)s * E_]) * mw[s];
  }
  part[((long)b * NCH + ch) * E_ + c] = sum;
}

__global__ __launch_bounds__(256)
void scan_final(const unsigned short* __restrict__ yt, const float* __restrict__ mixw,
                const float* __restrict__ mixb, const float* __restrict__ part,
                unsigned short* __restrict__ zt)
{
  const int b  = blockIdx.z;
  const int c  = blockIdx.y * 256 + threadIdx.x;
  const int ch = blockIdx.x;
  const int h  = c >> 6;
  float acc = 0.f;
  for (int p = 0; p < ch; ++p) acc += part[((long)b * NCH + p) * E_ + c];
  const unsigned short* yp = yt + ((long)b * S_ + ch * CS) * E_ + c;
  unsigned short*       zp = zt + ((long)b * S_ + ch * CS) * E_ + c;
  const float* mw = mixw + (long)h * S_ + ch * CS;
  const float* mb = mixb + (long)h * S_ + ch * CS;
  if (h < 8) {
    for (int s = 0; s < CS; ++s) {
      acc += bf2f(yp[(long)s * E_]);
      zp[(long)s * E_] = f2bf(fmaf(acc, mw[s], mb[s]));
    }
  } else {
    for (int s = 0; s < CS; ++s) {
      acc += bf2f(yp[(long)s * E_]) * mw[s];
      zp[(long)s * E_] = f2bf(acc + mb[s]);
    }
  }
}

// ---------------------------------------------------------------------------
extern "C" void kernel_launch(void* const* d_in, const int* in_sizes, int n_in,
                              void* d_out, int out_size, void* d_ws, size_t ws_size,
                              hipStream_t stream)
{
  (void)in_sizes; (void)n_in; (void)out_size; (void)ws_size;
  const float* x     = (const float*)d_in[0];
  const float* in_w  = (const float*)d_in[1];
  const float* in_b  = (const float*)d_in[2];
  const float* out_w = (const float*)d_in[3];
  const float* out_b = (const float*)d_in[4];
  const float* mix_w = (const float*)d_in[5];
  const float* mix_b = (const float*)d_in[6];

  char* ws = (char*)d_ws;
  unsigned short* Xt  = (unsigned short*)(ws);                            // 16 MB (reused as Zt)
  unsigned short* Yt  = (unsigned short*)(ws + (size_t)16 * 1024 * 1024); // 16 MB
  unsigned short* W1b = (unsigned short*)(ws + (size_t)32 * 1024 * 1024); // 2 MB
  unsigned short* W2b = (unsigned short*)(ws + (size_t)34 * 1024 * 1024); // 2 MB
  float*          part = (float*)(ws + (size_t)36 * 1024 * 1024);         // 512 KB
  unsigned short* Zt  = Xt;

  static int attr_set = 0;   // host-side only; idempotent, no stream ops
  hipFuncSetAttribute((const void*)gemm8p<0>, hipFuncAttributeMaxDynamicSharedMemorySize, 98304);
  hipFuncSetAttribute((const void*)gemm8p<1>, hipFuncAttributeMaxDynamicSharedMemorySize, 98304);
  (void)attr_set;

  convert_weights<<<dim3((2 * E_ * E_ / 4) / 256), 256, 0, stream>>>(in_w, out_w, W1b, W2b);

  transpose_convert<<<dim3(S_ / 64, E_ / 64, B_), 256, 0, stream>>>(x, Xt);

  // in_proj: Yt (8192 x 1024) = Xt * W1b^T + in_b
  gemm8p<0><<<dim3(256), 512, 98304, stream>>>(Xt, W1b, Yt, in_b);

  scan_part<<<dim3(NCH, E_ / 256, B_), 256, 0, stream>>>(Yt, mix_w, part);
  scan_final<<<dim3(NCH, E_ / 256, B_), 256, 0, stream>>>(Yt, mix_w, mix_b, part, Zt);

  // out_proj: out(b,e,s) = transposed-write of Zt * W2b^T + out_b
  gemm8p<1><<<dim3(256), 512, 98304, stream>>>(Zt, W2b, d_out, out_b);
}

// Round 3
// 85.253 us; speedup vs baseline: 1.1731x; 1.1246x over previous
//
#include <hip/hip_runtime.h>

// Problem constants
#define B_ 4
#define E_ 1024
#define S_ 2048
#define H_ 16
#define K_ 1024

#define NCH 32          // scan chunks along S
#define CS  (S_/NCH)    // 64

typedef __bf16 bf16x8 __attribute__((ext_vector_type(8)));
typedef float  f32x4  __attribute__((ext_vector_type(4)));

__device__ __forceinline__ unsigned short f2bf(float f) {
  unsigned u = __float_as_uint(f);
  u += 0x7fffu + ((u >> 16) & 1u);   // round-to-nearest-even
  return (unsigned short)(u >> 16);
}
__device__ __forceinline__ float bf2f(unsigned short h) {
  return __uint_as_float(((unsigned)h) << 16);
}

// ---------------------------------------------------------------------------
// fp32 -> bf16 weight conversion (in_w -> W1b, out_w -> W2b), no transpose.
// ---------------------------------------------------------------------------
__global__ __launch_bounds__(256)
void convert_weights(const float* __restrict__ a, const float* __restrict__ c,
                     unsigned short* __restrict__ wa, unsigned short* __restrict__ wb)
{
  const int per = (E_ * E_) / 4;
  int i = blockIdx.x * 256 + threadIdx.x;
  const float4* src = (i < per) ? (const float4*)a : (const float4*)c;
  unsigned short* dst = (i < per) ? wa : wb;
  int j = (i < per) ? i : i - per;
  float4 v = src[j];
  ushort4 o;
  o.x = f2bf(v.x); o.y = f2bf(v.y); o.z = f2bf(v.z); o.w = f2bf(v.w);
  *(ushort4*)(dst + (long)j * 4) = o;
}

// ---------------------------------------------------------------------------
// x (B,E,S) fp32 -> Xt (B,S,E) bf16 : LDS-tiled transpose + convert
// ---------------------------------------------------------------------------
__global__ __launch_bounds__(256)
void transpose_convert(const float* __restrict__ x, unsigned short* __restrict__ xt)
{
  __shared__ float t[64][65];
  const int b  = blockIdx.z;
  const int e0 = blockIdx.y * 64;
  const int s0 = blockIdx.x * 64;
  const int tx = threadIdx.x & 63, ty = threadIdx.x >> 6;

  const float* xp = x + ((long)b * E_ + e0) * S_ + s0;
#pragma unroll
  for (int r = 0; r < 16; ++r) {
    int row = r * 4 + ty;                          // e-offset within tile
    t[row][tx] = xp[(long)row * S_ + tx];
  }
  __syncthreads();
  unsigned short* xo = xt + ((long)b * S_ + s0) * E_ + e0;
#pragma unroll
  for (int p = 0; p < 2; ++p) {
    int s = p * 32 + (threadIdx.x >> 3);           // s-offset in tile
    int e = (threadIdx.x & 7) * 8;                 // e-offset in tile
    unsigned short v[8];
#pragma unroll
    for (int j = 0; j < 8; ++j) v[j] = f2bf(t[e + j][s]);
    *(ushort4*)(xo + (long)s * E_ + e)     = make_ushort4(v[0], v[1], v[2], v[3]);
    *(ushort4*)(xo + (long)s * E_ + e + 4) = make_ushort4(v[4], v[5], v[6], v[7]);
  }
}

// ---------------------------------------------------------------------------
// 8-phase GEMM: C (8192 x 1024) = A (8192 x 1024) * Bw (1024 x 1024)^T + bias
// BM=256, BN=128, BK=64; 512 thr (8 waves = 2M x 4N); double-buffered LDS
// 2 x (A[2][256][32] + B[2][128][32]) bf16 = 96 KiB, XOR-swizzled.
// Counted vmcnt(6) at even phases (T4); setprio around MFMA (T5).
// XCD-aware tiling (T1): xcd = bid&7 owns tm in {4*xcd..4*xcd+3} x all 8 tn,
// so each A-panel is fetched by exactly ONE XCD's L2 (A HBM 134MB -> 16.8MB).
// VARIANT 0: C = Yt bf16 row-major ld=1024, bias by col.
// VARIANT 1: C = out fp32 written transposed into (B_,E_,S_), bias by col.
// ---------------------------------------------------------------------------
#define BB1 49152      // buffer 1 byte offset (48 KiB per buffer)

__device__ __forceinline__ void stage_a(char* smem, const unsigned short* __restrict__ Ab,
                                        int bb, int t, int ks, int tid, int wid) {
#pragma unroll
  for (int j = 0; j < 2; ++j) {
    int chunk = j * 512 + tid;
    int row = chunk >> 2;
    int cb  = (chunk & 3) << 4;
    int cbs = cb ^ (((row >> 1) & 3) << 4);        // inverse(=same) swizzle on source
    const unsigned short* src = Ab + (long)row * K_ + t * 64 + ks * 32 + (cbs >> 1);
    __builtin_amdgcn_global_load_lds(
        (const __attribute__((address_space(1))) void*)src,
        (__attribute__((address_space(3))) void*)(smem + bb + ks * 16384 + j * 8192 + wid * 1024),
        16, 0, 0);
  }
}

__device__ __forceinline__ void stage_b(char* smem, const unsigned short* __restrict__ Bb,
                                        int bb, int t, int ks, int tid, int wid) {
  int row = tid >> 2;                              // 0..127
  int cb  = (tid & 3) << 4;
  int cbs = cb ^ (((row >> 1) & 3) << 4);
  const unsigned short* src = Bb + (long)row * K_ + t * 64 + ks * 32 + (cbs >> 1);
  __builtin_amdgcn_global_load_lds(
      (const __attribute__((address_space(1))) void*)src,
      (__attribute__((address_space(3))) void*)(smem + bb + 32768 + ks * 8192 + wid * 1024),
      16, 0, 0);
}

template<int MH>
__device__ __forceinline__ void phase_reads(const char* smem, int bb, int ks,
    int wm, int wn, int lr, int lg, bf16x8 af[4], bf16x8 bfr[2]) {
#pragma unroll
  for (int q = 0; q < 4; ++q) {
    int row = wm * 128 + (MH * 4 + q) * 16 + lr;
    int cb  = (lg * 16) ^ (((row >> 1) & 3) << 4);
    af[q] = *(const bf16x8*)(smem + bb + ks * 16384 + row * 64 + cb);
  }
  if (MH == 0) {
#pragma unroll
    for (int q = 0; q < 2; ++q) {
      int row = wn * 32 + q * 16 + lr;
      int cb  = (lg * 16) ^ (((row >> 1) & 3) << 4);
      bfr[q] = *(const bf16x8*)(smem + bb + 32768 + ks * 8192 + row * 64 + cb);
    }
  }
}

template<int MH>
__device__ __forceinline__ void phase_mfma(const bf16x8 af[4], const bf16x8 bfr[2],
                                           f32x4 acc[8][2]) {
  __builtin_amdgcn_s_setprio(1);
#pragma unroll
  for (int q = 0; q < 4; ++q)
#pragma unroll
    for (int nf = 0; nf < 2; ++nf)
      acc[MH * 4 + q][nf] = __builtin_amdgcn_mfma_f32_16x16x32_bf16(
          af[q], bfr[nf], acc[MH * 4 + q][nf], 0, 0, 0);
  __builtin_amdgcn_s_setprio(0);
}

#define FENCE asm volatile("" ::: "memory")
#define BAR do { FENCE; __builtin_amdgcn_s_barrier(); FENCE; } while (0)
#define VM(n) asm volatile("s_waitcnt vmcnt(" #n ")" ::: "memory")
#define NOWAIT (void)0

#define PH(bb, ks, mh, STAGE, WAIT) do {                        \
    bf16x8 af[4];                                               \
    phase_reads<mh>(smem, bb, ks, wm, wn, lr, lg, af, bfr);     \
    STAGE;                                                      \
    WAIT;                                                       \
    BAR;                                                        \
    asm volatile("s_waitcnt lgkmcnt(0)" ::: "memory");          \
    phase_mfma<mh>(af, bfr, acc);                               \
    BAR;                                                        \
  } while (0)

template<int VARIANT>
__global__ __launch_bounds__(512, 2)
void gemm8p(const unsigned short* __restrict__ A, const unsigned short* __restrict__ Bw,
            void* __restrict__ Cout, const float* __restrict__ bias)
{
  extern __shared__ char smem[];
  const int tid  = threadIdx.x;
  const int lane = tid & 63, wid = tid >> 6;
  const int wm = wid >> 2, wn = wid & 3;           // 2M x 4N waves
  const int lr = lane & 15, lg = lane >> 4;

  // T1 XCD-aware tiling: dispatch round-robins bid%8 across XCDs.
  // XCD x owns tm in {4x..4x+3} x tn in {0..7}: A-panels single-XCD,
  // per-XCD L2 working set = 4x512KB (A) + 2MB (B) = 4MB.
  const int bid = blockIdx.x;
  const int xcd = bid & 7;
  const int j8  = bid >> 3;                        // 0..31
  const int tm  = (xcd << 2) | (j8 & 3);           // 0..31
  const int tn  = j8 >> 2;                         // 0..7

  const unsigned short* Ab = A  + (long)tm * 256 * K_;
  const unsigned short* Bb = Bw + (long)tn * 128 * K_;

  f32x4 acc[8][2] = {};
  bf16x8 bfr[2];

  // Prologue: t0.Ak0 t0.Bk0 t0.Ak1 t0.Bk1 t1.Ak0 t1.Bk0 (9 loads), vmcnt(6)
  stage_a(smem, Ab, 0, 0, 0, tid, wid);
  stage_b(smem, Bb, 0, 0, 0, tid, wid);
  stage_a(smem, Ab, 0, 0, 1, tid, wid);
  stage_b(smem, Bb, 0, 0, 1, tid, wid);
  stage_a(smem, Ab, BB1, 1, 0, tid, wid);
  stage_b(smem, Bb, BB1, 1, 0, tid, wid);
  VM(6);
  BAR;

  for (int i = 0; i < 7; ++i) {                    // NI-1 full iterations
    const int t1 = 2 * i + 1, t2 = 2 * i + 2, t3 = 2 * i + 3;
    PH(0,   0, 0, stage_a(smem, Ab, BB1, t1, 1, tid, wid), NOWAIT);
    PH(0,   0, 1, stage_b(smem, Bb, BB1, t1, 1, tid, wid), VM(6));
    PH(0,   1, 0, stage_a(smem, Ab, 0,   t2, 0, tid, wid), NOWAIT);
    PH(0,   1, 1, stage_b(smem, Bb, 0,   t2, 0, tid, wid), VM(6));
    PH(BB1, 0, 0, stage_a(smem, Ab, 0,   t2, 1, tid, wid), NOWAIT);
    PH(BB1, 0, 1, stage_b(smem, Bb, 0,   t2, 1, tid, wid), VM(6));
    PH(BB1, 1, 0, stage_a(smem, Ab, BB1, t3, 0, tid, wid), NOWAIT);
    PH(BB1, 1, 1, stage_b(smem, Bb, BB1, t3, 0, tid, wid), VM(6));
  }
  // Final iteration (tiles 14,15): stage only t15.k1; drain 6 -> 3 -> 0.
  PH(0,   0, 0, stage_a(smem, Ab, BB1, 15, 1, tid, wid), NOWAIT);
  PH(0,   0, 1, stage_b(smem, Bb, BB1, 15, 1, tid, wid), VM(6));
  PH(0,   1, 0, NOWAIT, NOWAIT);
  PH(0,   1, 1, NOWAIT, VM(3));
  PH(BB1, 0, 0, NOWAIT, NOWAIT);
  PH(BB1, 0, 1, NOWAIT, VM(0));
  PH(BB1, 1, 0, NOWAIT, NOWAIT);
  PH(BB1, 1, 1, NOWAIT, NOWAIT);

  // Epilogue. C/D frag: col = lane&15, row = (lane>>4)*4 + j  [m89/m91]
#pragma unroll
  for (int nf = 0; nf < 2; ++nf) {
    const int c = tn * 128 + wn * 32 + nf * 16 + lr;
    const float bv = bias[c];
#pragma unroll
    for (int mf = 0; mf < 8; ++mf) {
      const int r0 = tm * 256 + wm * 128 + mf * 16 + lg * 4;
      if constexpr (VARIANT == 0) {
#pragma unroll
        for (int j = 0; j < 4; ++j)
          ((unsigned short*)Cout)[(long)(r0 + j) * E_ + c] = f2bf(acc[mf][nf][j] + bv);
      } else {
        const int s = r0 & (S_ - 1);
        const int b = r0 >> 11;                    // 256-row tile never crosses batch
        float4 v;
        v.x = acc[mf][nf][0] + bv; v.y = acc[mf][nf][1] + bv;
        v.z = acc[mf][nf][2] + bv; v.w = acc[mf][nf][3] + bv;
        *(float4*)((float*)Cout + ((long)b * E_ + c) * S_ + s) = v;
      }
    }
  }
}

// ---------------------------------------------------------------------------
// Mixing = causal prefix scan along S (two-pass, chunked).
// ---------------------------------------------------------------------------
__global__ __launch_bounds__(256)
void scan_part(const unsigned short* __restrict__ yt, const float* __restrict__ mixw,
               float* __restrict__ part)
{
  const int b  = blockIdx.z;
  const int c  = blockIdx.y * 256 + threadIdx.x;
  const int ch = blockIdx.x;
  const int h  = c >> 6;
  const unsigned short* yp = yt + ((long)b * S_ + ch * CS) * E_ + c;
  float sum = 0.f;
  if (h < 8) {
#pragma unroll 4
    for (int s = 0; s < CS; ++s) sum += bf2f(yp[(long)s * E_]);
  } else {
    const float* mw = mixw + (long)h * S_ + ch * CS;
#pragma unroll 4
    for (int s = 0; s < CS; ++s) sum += bf2f(yp[(long)s * E_]) * mw[s];
  }
  part[((long)b * NCH + ch) * E_ + c] = sum;
}

__global__ __launch_bounds__(256)
void scan_final(const unsigned short* __restrict__ yt, const float* __restrict__ mixw,
                const float* __restrict__ mixb, const float* __restrict__ part,
                unsigned short* __restrict__ zt)
{
  const int b  = blockIdx.z;
  const int c  = blockIdx.y * 256 + threadIdx.x;
  const int ch = blockIdx.x;
  const int h  = c >> 6;
  float acc = 0.f;
  for (int p = 0; p < ch; ++p) acc += part[((long)b * NCH + p) * E_ + c];
  const unsigned short* yp = yt + ((long)b * S_ + ch * CS) * E_ + c;
  unsigned short*       zp = zt + ((long)b * S_ + ch * CS) * E_ + c;
  const float* mw = mixw + (long)h * S_ + ch * CS;
  const float* mb = mixb + (long)h * S_ + ch * CS;
  if (h < 8) {
    for (int s = 0; s < CS; ++s) {
      acc += bf2f(yp[(long)s * E_]);
      zp[(long)s * E_] = f2bf(fmaf(acc, mw[s], mb[s]));
    }
  } else {
    for (int s = 0; s < CS; ++s) {
      acc += bf2f(yp[(long)s * E_]) * mw[s];
      zp[(long)s * E_] = f2bf(acc + mb[s]);
    }
  }
}

// ---------------------------------------------------------------------------
extern "C" void kernel_launch(void* const* d_in, const int* in_sizes, int n_in,
                              void* d_out, int out_size, void* d_ws, size_t ws_size,
                              hipStream_t stream)
{
  (void)in_sizes; (void)n_in; (void)out_size; (void)ws_size;
  const float* x     = (const float*)d_in[0];
  const float* in_w  = (const float*)d_in[1];
  const float* in_b  = (const float*)d_in[2];
  const float* out_w = (const float*)d_in[3];
  const float* out_b = (const float*)d_in[4];
  const float* mix_w = (const float*)d_in[5];
  const float* mix_b = (const float*)d_in[6];

  char* ws = (char*)d_ws;
  unsigned short* Xt  = (unsigned short*)(ws);                            // 16 MB (reused as Zt)
  unsigned short* Yt  = (unsigned short*)(ws + (size_t)16 * 1024 * 1024); // 16 MB
  unsigned short* W1b = (unsigned short*)(ws + (size_t)32 * 1024 * 1024); // 2 MB
  unsigned short* W2b = (unsigned short*)(ws + (size_t)34 * 1024 * 1024); // 2 MB
  float*          part = (float*)(ws + (size_t)36 * 1024 * 1024);         // 512 KB
  unsigned short* Zt  = Xt;

  hipFuncSetAttribute((const void*)gemm8p<0>, hipFuncAttributeMaxDynamicSharedMemorySize, 98304);
  hipFuncSetAttribute((const void*)gemm8p<1>, hipFuncAttributeMaxDynamicSharedMemorySize, 98304);

  convert_weights<<<dim3((2 * E_ * E_ / 4) / 256), 256, 0, stream>>>(in_w, out_w, W1b, W2b);

  transpose_convert<<<dim3(S_ / 64, E_ / 64, B_), 256, 0, stream>>>(x, Xt);

  // in_proj: Yt (8192 x 1024) = Xt * W1b^T + in_b
  gemm8p<0><<<dim3(256), 512, 98304, stream>>>(Xt, W1b, Yt, in_b);

  scan_part<<<dim3(NCH, E_ / 256, B_), 256, 0, stream>>>(Yt, mix_w, part);
  scan_final<<<dim3(NCH, E_ / 256, B_), 256, 0, stream>>>(Yt, mix_w, mix_b, part, Zt);

  // out_proj: out(b,e,s) = transposed-write of Zt * W2b^T + out_b
  gemm8p<1><<<dim3(256), 512, 98304, stream>>>(Zt, W2b, d_out, out_b);
}